// Round 3
// baseline (823.226 us; speedup 1.0000x reference)
//
#include <hip/hip_runtime.h>
#include <math.h>

#define F 128
#define R 16
#define O 12
#define NB 32   // nodes per block in fused MLP
#define EB 8    // edges per staging batch in gather (double-buffered)

// ---------------- small utility kernels ----------------
__global__ void zero_int_kernel(int* __restrict__ p, int n) {
    int i = blockIdx.x * blockDim.x + threadIdx.x;
    if (i < n) p[i] = 0;
}

// ---------------- CSR build: histogram ----------------
__global__ __launch_bounds__(256) void hist_kernel(
    const int* __restrict__ idx, int* __restrict__ cnt, int E)
{
    int i = blockIdx.x * blockDim.x + threadIdx.x;
    int stride = gridDim.x * blockDim.x;
    for (; i < E; i += stride) atomicAdd(&cnt[idx[i]], 1);
}

// ---------------- CSR build: exclusive scan (single block) ----------------
__global__ __launch_bounds__(1024) void scan_kernel(
    const int* __restrict__ cnt, int* __restrict__ off,
    int* __restrict__ cur, int N, int E)
{
    __shared__ int part[1024];
    int t = threadIdx.x;
    const int per = (N + 1023) / 1024;
    int s0 = t * per;
    int s = 0;
    for (int i = 0; i < per; i++) { int k = s0 + i; if (k < N) s += cnt[k]; }
    part[t] = s;
    __syncthreads();
    for (int d = 1; d < 1024; d <<= 1) {
        int v = (t >= d) ? part[t - d] : 0;
        __syncthreads();
        part[t] += v;
        __syncthreads();
    }
    int run = (t == 0) ? 0 : part[t - 1];
    for (int i = 0; i < per; i++) {
        int k = s0 + i;
        if (k < N) { off[k] = run; cur[k] = run; run += cnt[k]; }
    }
    if (t == 0) off[N] = E;
}

// ---------------- CSR build: fill edge lists ----------------
__global__ __launch_bounds__(256) void fill_kernel(
    const int* __restrict__ idx, int* __restrict__ cur,
    int* __restrict__ csr, int E)
{
    int i = blockIdx.x * blockDim.x + threadIdx.x;
    int stride = gridDim.x * blockDim.x;
    for (; i < E; i += stride) {
        int n = idx[i];
        int p = atomicAdd(&cur[n], 1);
        csr[p] = i;
    }
}

__device__ __forceinline__ float dot16(const float4* r, const float4* Wv) {
    float s = 0.f;
    #pragma unroll
    for (int q = 0; q < 4; q++)
        s += r[q].x * Wv[q].x + r[q].y * Wv[q].y + r[q].z * Wv[q].z + r[q].w * Wv[q].w;
    return s;
}

// direct global->LDS DMA: per-lane global src, wave-uniform LDS base + lane*16
__device__ __forceinline__ void gld_lds16(const float* g, float* l) {
    __builtin_amdgcn_global_load_lds(
        (const __attribute__((address_space(1))) void*)g,
        (__attribute__((address_space(3))) void*)l,
        16, 0, 0);
}

// ---------------- fused rbf-linear * gate -> GATHER (no atomics) ----------------
// v5: (a) rbf rows are wave-uniform per edge -> readfirstlane the edge id and
// load the 64B row via the SCALAR path (register prefetch, depth 1). Removes
// the rbf DMA and ALL per-edge LDS broadcast reads (was ~2.6 GB LDS traffic).
// (b) m staging double-buffered: issue batch k+1's 4 DMAs before computing
// batch k, wait vmcnt(4) (counted, never drain mid-loop). csr ids for k+1
// broadcast-loaded a batch ahead so the csr->address chain is off-path.
// In-flight data lives in LDS (vmcnt-tracked, ~0 VGPR) -> no spill risk.
__global__ __launch_bounds__(256) void gather_kernel(
    const float* __restrict__ m, const float* __restrict__ rbf,
    const int* __restrict__ csr, const int* __restrict__ off,
    const float* __restrict__ Wrbf, float* __restrict__ A, int N)
{
    __shared__ float m_buf[4 * 2 * EB * F];   // 4 waves x 2 bufs x 4KB = 32 KB
    const int lane = threadIdx.x & 63;
    const int w = threadIdx.x >> 6;
    const int n = blockIdx.x * 4 + w;
    if (n >= N) return;

    float* mw = m_buf + w * (2 * EB * F);

    const int f0 = lane << 1;
    float4 W0[4], W1[4];
    #pragma unroll
    for (int q = 0; q < 4; q++) {
        W0[q] = *(const float4*)(Wrbf + (size_t)f0 * R + q * 4);
        W1[q] = *(const float4*)(Wrbf + (size_t)(f0 + 1) * R + q * 4);
    }

    float a0 = 0.f, a1 = 0.f;
    const int jb = off[n], je = off[n + 1];
    const int last = je - 1;

    if (jb < je) {
        int ec[EB], en[EB];   // current / next batch edge ids (SGPR, all lanes)
        #pragma unroll
        for (int k = 0; k < EB; k++) {
            int jj = jb + k; if (jj > last) jj = last;       // clamp: dup, unread
            ec[k] = __builtin_amdgcn_readfirstlane(csr[jj]);
        }
        #pragma unroll
        for (int k = 0; k < EB; k++) en[k] = ec[k];

        // stage batch 0 into buffer 0 (4 DMAs, each 2 rows: lanes 0-31 row 2k)
        #pragma unroll
        for (int k = 0; k < EB / 2; k++) {
            int e = (lane < 32) ? ec[2 * k] : ec[2 * k + 1];
            gld_lds16(m + (size_t)e * F + ((lane & 31) << 2), mw + k * 2 * F);
        }

        int buf = 0;
        for (int j0 = jb; j0 < je; j0 += EB) {
            const int c = (je - j0 < EB) ? (je - j0) : EB;
            const int jn = j0 + EB;
            const bool more = (jn < je);

            if (more) {
                #pragma unroll
                for (int k = 0; k < EB; k++) {
                    int jj = jn + k; if (jj > last) jj = last;
                    en[k] = __builtin_amdgcn_readfirstlane(csr[jj]);
                }
                // prior reads of the dest buffer are long retired; cheap fence
                asm volatile("s_waitcnt lgkmcnt(0)" ::: "memory");
                float* dst = mw + (buf ^ 1) * EB * F;
                #pragma unroll
                for (int k = 0; k < EB / 2; k++) {
                    int e = (lane < 32) ? en[2 * k] : en[2 * k + 1];
                    gld_lds16(m + (size_t)e * F + ((lane & 31) << 2), dst + k * 2 * F);
                }
                asm volatile("s_waitcnt vmcnt(4)" ::: "memory");   // cur batch landed
            } else {
                asm volatile("s_waitcnt vmcnt(0)" ::: "memory");
            }

            const float* src = mw + buf * EB * F;

            // rbf scalar-path pipeline: depth-1 register prefetch
            float4 ra[4], rb[4];
            {
                const float4* p = (const float4*)(rbf + (size_t)ec[0] * R);
                ra[0] = p[0]; ra[1] = p[1]; ra[2] = p[2]; ra[3] = p[3];
            }
            #pragma unroll
            for (int r = 0; r < EB; r++) {
                if (r >= c) break;                       // wave-uniform
                // prefetch edge r+1's rbf row into the alternate regs
                {
                    const float4* p = (const float4*)(rbf + (size_t)ec[(r + 1) & (EB - 1)] * R);
                    float4* nxt = (r & 1) ? ra : rb;     // r is compile-time (unrolled)
                    nxt[0] = p[0]; nxt[1] = p[1]; nxt[2] = p[2]; nxt[3] = p[3];
                }
                const float4* cur4 = (r & 1) ? rb : ra;
                float2 mv = *(const float2*)(src + r * F + f0);  // 8B/lane: conflict-free
                a0 += dot16(cur4, W0) * mv.x;
                a1 += dot16(cur4, W1) * mv.y;
            }

            #pragma unroll
            for (int k = 0; k < EB; k++) ec[k] = en[k];
            buf ^= 1;
        }
    }

    *(float2*)(A + (size_t)n * F + f0) = make_float2(a0, a1);
}

// ---------------- fused MLP (3 layers) + projection ----------------
// 32 nodes per block, 625 blocks. Weights staged per layer into 64KB LDS;
// activations in 16KB LDS updated IN-PLACE (rows are wave-local -> no
// inter-layer sync needed). 80KB LDS -> 2 blocks/CU.
__global__ __launch_bounds__(256) void mlp_fused(
    const float* __restrict__ A, const float* __restrict__ dW,
    const float* __restrict__ db, const float* __restrict__ Wout,
    float* __restrict__ out, int N)
{
    __shared__ float Ws[F * F];     // 64 KB
    __shared__ float act[NB * F];   // 16 KB
    int t = threadIdx.x;
    int base = blockIdx.x * NB;
    int j = t & 15, i = t >> 4;

    int  n0[2]; bool ok[2];
    #pragma unroll
    for (int k = 0; k < 2; k++) { n0[k] = base + i + 16 * k; ok[k] = n0[k] < N; }

    for (int l = 0; l < 3; l++) {
        __syncthreads();
        for (int s = t; s < F * F / 4; s += 256) {
            int g = s >> 5, c = s & 31;
            float4 v = *(const float4*)(dW + (size_t)l * F * F + g * F + (c << 2));
            *(float4*)(Ws + g * F + ((c ^ (g & 31)) << 2)) = v;
        }
        __syncthreads();

        float acc[2][8];
        #pragma unroll
        for (int k = 0; k < 2; k++)
            #pragma unroll
            for (int mm = 0; mm < 8; mm++) acc[k][mm] = 0.f;

        for (int c = 0; c < 32; c++) {
            int f = c << 2;
            float4 av[2];
            #pragma unroll
            for (int k = 0; k < 2; k++) {
                if (l == 0)
                    av[k] = ok[k] ? *(const float4*)(A + (size_t)n0[k] * F + f)
                                  : make_float4(0.f, 0.f, 0.f, 0.f);
                else
                    av[k] = *(const float4*)(act + (i + 16 * k) * F + f);
            }
            float4 wv[8];
            #pragma unroll
            for (int mm = 0; mm < 8; mm++) {
                int g = j + 16 * mm;
                wv[mm] = *(const float4*)(Ws + g * F + ((c ^ (g & 31)) << 2));
            }
            #pragma unroll
            for (int k = 0; k < 2; k++)
                #pragma unroll
                for (int mm = 0; mm < 8; mm++)
                    acc[k][mm] += av[k].x * wv[mm].x + av[k].y * wv[mm].y +
                                  av[k].z * wv[mm].z + av[k].w * wv[mm].w;
        }

        #pragma unroll
        for (int mm = 0; mm < 8; mm++) {
            int g = j + 16 * mm;
            float bias = db[l * F + g];
            #pragma unroll
            for (int k = 0; k < 2; k++) {
                float x = acc[k][mm] + bias;
                act[(i + 16 * k) * F + g] = x / (1.f + __expf(-x));
            }
        }
    }

    // ---- projection ----
    __syncthreads();
    for (int s = t; s < O * F / 4; s += 256)
        ((float4*)Ws)[s] = ((const float4*)Wout)[s];
    __syncthreads();

    int nl = t >> 3;                 // 0..31
    int oq = t & 7;
    int n = base + nl;
    if (n < N) {
        float s0 = 0.f, s1 = 0.f;
        for (int f = 0; f < F; f += 4) {
            float4 a  = *(const float4*)(act + nl * F + f);
            float4 w0 = *(const float4*)(Ws + oq * F + f);
            s0 += a.x * w0.x + a.y * w0.y + a.z * w0.z + a.w * w0.w;
            if (oq < 4) {
                float4 w1 = *(const float4*)(Ws + (8 + oq) * F + f);
                s1 += a.x * w1.x + a.y * w1.y + a.z * w1.z + a.w * w1.w;
            }
        }
        out[(size_t)n * O + oq] = s0;
        if (oq < 4) out[(size_t)n * O + 8 + oq] = s1;
    }
}

extern "C" void kernel_launch(void* const* d_in, const int* in_sizes, int n_in,
                              void* d_out, int out_size, void* d_ws, size_t ws_size,
                              hipStream_t stream)
{
    const float* m    = (const float*)d_in[0];
    const float* rbf  = (const float*)d_in[1];
    const int*   aei  = (const int*)d_in[2];
    const float* Wrbf = (const float*)d_in[3];
    const float* dW   = (const float*)d_in[4];
    const float* db   = (const float*)d_in[5];
    const float* Wout = (const float*)d_in[6];
    float* out = (float*)d_out;

    int E = in_sizes[0] / F;     // 640000
    int N = out_size / O;        // 20000

    float* A = (float*)d_ws;
    int* csr = (int*)(A + (size_t)N * F);
    int* cnt = csr + E;
    int* cur = cnt + N;
    int* off = cur + N;

    const int* idx1 = aei + E;   // row 1 = receiving atoms

    zero_int_kernel<<<(N + 255) / 256, 256, 0, stream>>>(cnt, N);
    hist_kernel<<<1024, 256, 0, stream>>>(idx1, cnt, E);
    scan_kernel<<<1, 1024, 0, stream>>>(cnt, off, cur, N, E);
    fill_kernel<<<1024, 256, 0, stream>>>(idx1, cur, csr, E);
    gather_kernel<<<(N + 3) / 4, 256, 0, stream>>>(m, rbf, csr, off, Wrbf, A, N);

    mlp_fused<<<(N + NB - 1) / NB, 256, 0, stream>>>(A, dW, db, Wout, out, N);
}